// Round 7
// baseline (127.925 us; speedup 1.0000x reference)
//
#include <hip/hip_runtime.h>

// Problem constants (from reference)
#define VOCAB 50000
#define SEQ   2048
#define BATCH 64
#define DIM   256
#define H1    100
#define H2    150
#define HASH  8192            // packed hash slots (load factor ~0.25)
#define EMPTY 0xFFFFFFFFu     // token field 0xFFFF is an impossible token (<50000)
#define NCH   8               // chunks per row
#define CHUNK (SEQ / NCH)     // 256
#define NT    1024
#define NWAVE (NT / 64)       // 16

// ---------------------------------------------------------------------------
// Kernel 1: 512 blocks = (row r, chunk c).
//   - full-row tf histogram in a PACKED LDS hash: entry = (count<<16)|token.
//     Tokens < 50000 < 0xFFFF so EMPTY=0xFFFFFFFF is unambiguous; max count
//     2048 can't overflow 16 bits. Common case: 1 ds_read + 1 atomic.
//   - tf-idf scores for its 256-token chunk
//   - emb gather-pool: 4-way unrolled, 4 independent float4 accumulators
//     (>=4 outstanding 1KB loads/wave), launch_bounds(1024,8) pins VGPR<=64
//     so 2 blocks/CU (32 waves/CU) residency is preserved.
// No fences / device atomics (R5 lesson); kernel boundary = device sync.
// LDS: hash 32K + tokc 1K + sc 1K + wacc 16K = 50 KB.
// ---------------------------------------------------------------------------
__global__ __launch_bounds__(1024, 8)
void k_gather(const int* __restrict__ x,
              const float* __restrict__ emb,
              const float* __restrict__ idf,
              float* __restrict__ partials) {    // [BATCH*NCH][DIM]
    __shared__ unsigned hh[HASH];       // 32 KB packed (count<<16)|token
    __shared__ int      tokc[CHUNK];    //  1 KB chunk tokens
    __shared__ float    sc[CHUNK];      //  1 KB chunk scores
    __shared__ float    wacc[NWAVE][DIM]; // 16 KB

    const int bx = blockIdx.x;          // 0..511
    const int r  = bx >> 3;             // batch row
    const int c  = bx & (NCH - 1);      // chunk
    const int t  = threadIdx.x;         // 0..1023
    const int w  = t >> 6, lane = t & 63;
    const int s0 = c * CHUNK;

    // ---- init hash + stage chunk tokens ----
#pragma unroll
    for (int n = 0; n < HASH / NT; ++n) hh[n * NT + t] = EMPTY;
    if (t < CHUNK) tokc[t] = x[(s0 + t) * BATCH + r];
    __syncthreads();

    // ---- tf histogram insert (full row, read x directly; 2 tokens/thread) ----
#pragma unroll
    for (int n = 0; n < SEQ / NT; ++n) {
        const int s = n * NT + t;
        const unsigned mytok = (unsigned)x[s * BATCH + r];
        unsigned h = (mytok * 2654435761u) >> 19;     // top 13 bits
        while (true) {
            const unsigned cur = hh[h];
            if ((cur & 0xFFFFu) == mytok) {           // EMPTY can't match
                atomicAdd(&hh[h], 1u << 16);
                break;
            }
            if (cur == EMPTY) {
                const unsigned prev = atomicCAS(&hh[h], EMPTY, (1u << 16) | mytok);
                if (prev == EMPTY) break;
                if ((prev & 0xFFFFu) == mytok) { atomicAdd(&hh[h], 1u << 16); break; }
                continue;                              // slot now has another token
            }
            h = (h + 1) & (HASH - 1);
        }
    }
    __syncthreads();

    // ---- scores for this chunk (read-only probe) ----
    if (t < CHUNK) {
        const unsigned mytok = (unsigned)tokc[t];
        unsigned h = (mytok * 2654435761u) >> 19;
        while ((hh[h] & 0xFFFFu) != mytok) h = (h + 1) & (HASH - 1);
        const float cnt = (float)(hh[h] >> 16);
        sc[t] = (mytok == 0u) ? 0.0f : cnt * idf[mytok];
    }
    __syncthreads();

    // ---- gather-pool: wave w owns 16 s-positions, 4-way unrolled ----
    {
        const float4* embv = (const float4*)emb;   // emb row = 64 float4
        float4 a0 = make_float4(0.f, 0.f, 0.f, 0.f);
        float4 a1 = make_float4(0.f, 0.f, 0.f, 0.f);
        float4 a2 = make_float4(0.f, 0.f, 0.f, 0.f);
        float4 a3 = make_float4(0.f, 0.f, 0.f, 0.f);
        const int i0 = w * (CHUNK / NWAVE);        // 16 positions per wave
#pragma unroll
        for (int i = 0; i < CHUNK / NWAVE; i += 4) {
            const int   t0 = tokc[i0 + i + 0], t1 = tokc[i0 + i + 1];
            const int   t2 = tokc[i0 + i + 2], t3 = tokc[i0 + i + 3];
            const float s0v = sc[i0 + i + 0], s1v = sc[i0 + i + 1];
            const float s2v = sc[i0 + i + 2], s3v = sc[i0 + i + 3];
            const float4 v0 = embv[(size_t)t0 * (DIM / 4) + lane];
            const float4 v1 = embv[(size_t)t1 * (DIM / 4) + lane];
            const float4 v2 = embv[(size_t)t2 * (DIM / 4) + lane];
            const float4 v3 = embv[(size_t)t3 * (DIM / 4) + lane];
            a0.x = fmaf(v0.x, s0v, a0.x); a0.y = fmaf(v0.y, s0v, a0.y);
            a0.z = fmaf(v0.z, s0v, a0.z); a0.w = fmaf(v0.w, s0v, a0.w);
            a1.x = fmaf(v1.x, s1v, a1.x); a1.y = fmaf(v1.y, s1v, a1.y);
            a1.z = fmaf(v1.z, s1v, a1.z); a1.w = fmaf(v1.w, s1v, a1.w);
            a2.x = fmaf(v2.x, s2v, a2.x); a2.y = fmaf(v2.y, s2v, a2.y);
            a2.z = fmaf(v2.z, s2v, a2.z); a2.w = fmaf(v2.w, s2v, a2.w);
            a3.x = fmaf(v3.x, s3v, a3.x); a3.y = fmaf(v3.y, s3v, a3.y);
            a3.z = fmaf(v3.z, s3v, a3.z); a3.w = fmaf(v3.w, s3v, a3.w);
        }
        float4 acc;
        acc.x = (a0.x + a1.x) + (a2.x + a3.x);
        acc.y = (a0.y + a1.y) + (a2.y + a3.y);
        acc.z = (a0.z + a1.z) + (a2.z + a3.z);
        acc.w = (a0.w + a1.w) + (a2.w + a3.w);
        ((float4*)wacc[w])[lane] = acc;
    }
    __syncthreads();

    // ---- reduce waves -> chunk partial (coalesced 1 KB write) ----
    if (t < DIM) {
        float a = 0.0f;
#pragma unroll
        for (int i = 0; i < NWAVE; ++i) a += wacc[i][t];
        partials[(size_t)bx * DIM + t] = a;
    }
}

// ---------------------------------------------------------------------------
// Kernel 2: per-row partial reduce + 3-layer MLP + softmax (proven tail).
// 64 blocks x 1024 threads.
// ---------------------------------------------------------------------------
__global__ __launch_bounds__(1024)
void k_mlp(const float* __restrict__ partials,
           const float* __restrict__ W1, const float* __restrict__ b1,
           const float* __restrict__ W2, const float* __restrict__ b2,
           const float* __restrict__ W3, const float* __restrict__ b3,
           float* __restrict__ out) {
    __shared__ float pooled[DIM];
    __shared__ float hp1[128][4];
    __shared__ float h1s[112];
    __shared__ float hp2[H2][4];
    __shared__ float h2s[152];
    __shared__ float lg[2];
    const int r = blockIdx.x;
    const int t = threadIdx.x;

    if (t < DIM) {
        float a = 0.0f;
#pragma unroll
        for (int cc = 0; cc < NCH; ++cc)
            a += partials[((size_t)r * NCH + cc) * DIM + t];
        pooled[t] = a;
    }
    __syncthreads();

    // stage 1 (100 neurons, k=256): 4 threads/neuron
    if (t < 512) {
        const int j = t >> 2;            // 0..127 (j<100 active)
        const int q = t & 3;             // k-quarter
        if (j < H1) {
            const float4* wv = (const float4*)(W1 + j * DIM + q * 64);
            const float4* pv = ((const float4*)pooled) + q * 16;
            float a = 0.0f;
#pragma unroll
            for (int i = 0; i < 16; ++i) {
                const float4 ww = wv[i];
                const float4 pp = pv[i];
                a += ww.x * pp.x + ww.y * pp.y + ww.z * pp.z + ww.w * pp.w;
            }
            hp1[j][q] = a;
        }
    }
    __syncthreads();
    if (t < H1)
        h1s[t] = fmaxf(hp1[t][0] + hp1[t][1] + hp1[t][2] + hp1[t][3] + b1[t], 0.0f);
    __syncthreads();

    // stage 2 (150 neurons, k=100): 4 threads/neuron
    if (t < 600) {
        const int j = t >> 2;            // 0..149
        const int q = t & 3;             // k-chunk of 25
        const float* wv = W2 + j * H1 + q * 25;
        float a = 0.0f;
#pragma unroll
        for (int i = 0; i < 25; ++i)
            a = fmaf(wv[i], h1s[q * 25 + i], a);
        hp2[j][q] = a;
    }
    __syncthreads();
    if (t < H2)
        h2s[t] = fmaxf(hp2[t][0] + hp2[t][1] + hp2[t][2] + hp2[t][3] + b2[t], 0.0f);
    __syncthreads();

    // logits + softmax
    if (t < 2) {
        const float* wv = W3 + t * H2;
        float a = b3[t];
        for (int k = 0; k < H2; ++k) a = fmaf(wv[k], h2s[k], a);
        lg[t] = a;
    }
    __syncthreads();
    if (t == 0) {
        const float m  = fmaxf(lg[0], lg[1]);
        const float e0 = __expf(lg[0] - m);
        const float e1 = __expf(lg[1] - m);
        const float inv = 1.0f / (e0 + e1);
        out[r * 2 + 0] = e0 * inv;
        out[r * 2 + 1] = e1 * inv;
    }
}

// ---------------------------------------------------------------------------
extern "C" void kernel_launch(void* const* d_in, const int* in_sizes, int n_in,
                              void* d_out, int out_size, void* d_ws, size_t ws_size,
                              hipStream_t stream) {
    const int*   x   = (const int*)  d_in[0];   // [SEQ, BATCH] int32
    const float* emb = (const float*)d_in[1];   // [VOCAB, DIM]
    const float* idf = (const float*)d_in[2];   // [VOCAB]
    const float* W1  = (const float*)d_in[3];   // [H1, DIM]
    const float* b1  = (const float*)d_in[4];   // [H1]
    const float* W2  = (const float*)d_in[5];   // [H2, H1]
    const float* b2  = (const float*)d_in[6];   // [H2]
    const float* W3  = (const float*)d_in[7];   // [2, H2]
    const float* b3  = (const float*)d_in[8];   // [2]
    float* out = (float*)d_out;                 // [BATCH, 2]

    float* partials = (float*)d_ws;             // [512][256] = 512 KB

    k_gather<<<BATCH * NCH, NT, 0, stream>>>(x, emb, idf, partials);
    k_mlp   <<<BATCH, NT, 0, stream>>>(partials, W1, b1, W2, b2, W3, b3, out);
}